// Round 7
// baseline (192.279 us; speedup 1.0000x reference)
//
#include <hip/hip_runtime.h>

// ---------------- types / helpers ----------------
using bf16x8 = __attribute__((ext_vector_type(8))) short;
using f32x4  = __attribute__((ext_vector_type(4))) float;

static __device__ inline unsigned short f2bf(float f) {
  unsigned int u = __float_as_uint(f);
  u += 0x7fffu + ((u >> 16) & 1u);          // round-to-nearest-even
  return (unsigned short)(u >> 16);
}
static __device__ inline unsigned int pk2(float a, float b) {
  return (unsigned int)f2bf(a) | ((unsigned int)f2bf(b) << 16);
}

// Barrier draining LDS ops only; global loads (vmcnt) stay in flight.
#define BAR_LGKM() { asm volatile("s_waitcnt lgkmcnt(0)" ::: "memory"); \
                     __builtin_amdgcn_sched_barrier(0); \
                     __builtin_amdgcn_s_barrier(); }

// butterfly reductions across the 16-lane DPP row (row_ror 1,2,4,8)
#define ROW16_MAX(x) { \
  { int _t = __builtin_amdgcn_update_dpp(0, __float_as_int(x), 0x121, 0xf, 0xf, true); x = fmaxf(x, __int_as_float(_t)); } \
  { int _t = __builtin_amdgcn_update_dpp(0, __float_as_int(x), 0x122, 0xf, 0xf, true); x = fmaxf(x, __int_as_float(_t)); } \
  { int _t = __builtin_amdgcn_update_dpp(0, __float_as_int(x), 0x124, 0xf, 0xf, true); x = fmaxf(x, __int_as_float(_t)); } \
  { int _t = __builtin_amdgcn_update_dpp(0, __float_as_int(x), 0x128, 0xf, 0xf, true); x = fmaxf(x, __int_as_float(_t)); } }
#define ROW16_SUM(x) { \
  { int _t = __builtin_amdgcn_update_dpp(0, __float_as_int(x), 0x121, 0xf, 0xf, true); x += __int_as_float(_t); } \
  { int _t = __builtin_amdgcn_update_dpp(0, __float_as_int(x), 0x122, 0xf, 0xf, true); x += __int_as_float(_t); } \
  { int _t = __builtin_amdgcn_update_dpp(0, __float_as_int(x), 0x124, 0xf, 0xf, true); x += __int_as_float(_t); } \
  { int _t = __builtin_amdgcn_update_dpp(0, __float_as_int(x), 0x128, 0xf, 0xf, true); x += __int_as_float(_t); } }

// ---------------- kernel 0: weight prep (transpose -> bf16) ----------------
__global__ __launch_bounds__(256) void prep_kernel(
    const float* __restrict__ Wq, const float* __restrict__ Wk, const float* __restrict__ Wv,
    const float* __restrict__ Wo, const float* __restrict__ bq, const float* __restrict__ bk,
    const float* __restrict__ bv,
    unsigned short* __restrict__ Wt, unsigned short* __restrict__ Wot, float* __restrict__ bqkv)
{
  int idx = blockIdx.x * 256 + threadIdx.x;
  if (idx < 192 * 1024) {
    int n = idx >> 10, k = idx & 1023;
    const float* W = (n < 64) ? Wq : (n < 128) ? Wk : Wv;
    Wt[idx] = f2bf(W[k * 64 + (n & 63)]);
  } else if (idx < 192 * 1024 + 1024 * 64) {
    int j = idx - 192 * 1024;
    int n = j >> 6, k = j & 63;
    Wot[j] = f2bf(Wo[k * 1024 + n]);
  } else if (idx < 192 * 1024 + 1024 * 64 + 192) {
    int n = idx - (192 * 1024 + 1024 * 64);
    bqkv[n] = (n < 64) ? bq[n] : (n < 128) ? bk[n - 64] : bv[n - 128];
  }
}

// ---------------- fused kernel: QKV proj + banded attention + out proj ----------------
// Block = 64 q-rows, 512 threads = 8 waves. LDS 78.3 KB -> 2 blocks/CU so a
// second block's phase-1 (fetch+MFMA) overlaps this block's phase-2/3.
// LDS map (bytes):
//   phase 1: A dbuf [0, 30720), B dbuf [30720, 61440)   (BK=32, pad 40 shorts)
//   phase 2: Kl [0, 27648), Vt [27648, 55296),
//            PsU [55296, 76800)  time-muxed: Qtmp -> P -> Obf
//   always : Mx [76800], Lx [77312], biasL [77824..78340)   (outside p1 region)
__global__ __launch_bounds__(512, 4) void fused_attn(
    const float* __restrict__ X, const unsigned short* __restrict__ Wt,
    const float* __restrict__ bqkv, const float* __restrict__ bias,
    const unsigned short* __restrict__ Wot, const float* __restrict__ bo,
    float* __restrict__ out)
{
  __shared__ __align__(16) char smem[78848];
  unsigned short* const Kl  = (unsigned short*)(smem);
  unsigned short* const Vt  = (unsigned short*)(smem + 27648);
  unsigned short* const PsU = (unsigned short*)(smem + 55296);
  float* const Mx    = (float*)(smem + 76800);
  float* const Lx    = (float*)(smem + 77312);
  float* const biasL = (float*)(smem + 77824);
  unsigned short* const As_ = (unsigned short*)(smem);
  unsigned short* const Bs_ = (unsigned short*)(smem + 30720);

  int t = threadIdx.x;
  int lane = t & 63, w = t >> 6;
  int col = lane & 15, quad = lane >> 4, q4 = quad * 4;
  // XCD swizzle: blockIdx round-robins XCDs; map so each XCD gets one batch's
  // 32 contiguous q-tiles -> halo re-reads hit that XCD's L2.
  int L = ((blockIdx.x & 7) << 5) | (blockIdx.x >> 3);
  int b = L >> 5;                    // batch
  int i0 = (L & 31) * 64;            // first q row (batch coords)
  const float* xbase = X + (size_t)(b << 11) * 1024;

  if (t < 129) biasL[t] = bias[1984 + t];   // region not touched by phase 1

  // ---- phase 1: window GEMM [192 rows] x [192 qkv] x K=1024, BK=32 dbuf ----
  int wm = w >> 2, wn = w & 3;       // wave tile: 96 rows x 48 cols
  f32x4 acc[6][3] = {};
  int tr = t >> 3, c4 = t & 7;       // 3 staging tasks: rows tr, tr+64, tr+128
  int offA[3], offB[3];
  #pragma unroll
  for (int i = 0; i < 3; ++i) {
    int row = i * 64 + tr;           // window row 0..191
    int jb = i0 - 64 + row;
    int jc = jb < 0 ? 0 : (jb > 2047 ? 2047 : jb);
    offA[i] = jc * 1024 + c4 * 4;
    offB[i] = row * 1024 + c4 * 4;
  }
  float bov[3];
  #pragma unroll
  for (int nt = 0; nt < 3; ++nt) bov[nt] = bqkv[wn * 48 + nt * 16 + col];

  float4 pA[3]; uint2 pB[3];
  #pragma unroll
  for (int i = 0; i < 3; ++i) {
    pA[i] = *(const float4*)(xbase + offA[i]);
    pB[i] = *(const uint2*)(Wt + offB[i]);
  }
  for (int ks = 0; ks < 32; ++ks) {
    unsigned short* A  = As_ + (ks & 1) * 7680;
    unsigned short* Bb = Bs_ + (ks & 1) * 7680;
    #pragma unroll
    for (int i = 0; i < 3; ++i) {    // store staged regs -> LDS[cur]
      *(uint2*)(A  + (i * 64 + tr) * 40 + c4 * 4) =
          make_uint2(pk2(pA[i].x, pA[i].y), pk2(pA[i].z, pA[i].w));
      *(uint2*)(Bb + (i * 64 + tr) * 40 + c4 * 4) = pB[i];
    }
    if (ks + 1 < 32) {               // issue next tile's loads before barrier
      #pragma unroll
      for (int i = 0; i < 3; ++i) {
        pA[i] = *(const float4*)(xbase + offA[i] + (ks + 1) * 32);
        pB[i] = *(const uint2*)(Wt + offB[i] + (ks + 1) * 32);
      }
    }
    BAR_LGKM();
    // single barrier/iter safe: a wave's buf-X ds_reads drain (lgkmcnt 0)
    // before it signals the next barrier; writes to buf-X happen 2 iters
    // later, after that barrier.
    int ko = quad * 8;
    bf16x8 bfr[3];
    #pragma unroll
    for (int nt = 0; nt < 3; ++nt)
      bfr[nt] = *(const bf16x8*)(Bb + ((wn * 3 + nt) * 16 + col) * 40 + ko);
    #pragma unroll
    for (int mt = 0; mt < 6; ++mt) {
      bf16x8 afr = *(const bf16x8*)(A + ((wm * 6 + mt) * 16 + col) * 40 + ko);
      #pragma unroll
      for (int nt = 0; nt < 3; ++nt)
        acc[mt][nt] = __builtin_amdgcn_mfma_f32_16x16x32_bf16(afr, bfr[nt], acc[mt][nt], 0, 0, 0);
    }
  }
  BAR_LGKM();        // all last-buf ds_reads done before LDS repurpose

  // ---- phase 1b: accumulators (+bias, ->bf16) into phase-2 layouts ----
  // Q (middle 64 rows) -> PsU[0..4607] as [64][72]; K -> Kl; V -> Vt (transposed)
  #pragma unroll
  for (int mt = 0; mt < 6; ++mt) {
    #pragma unroll
    for (int nt = 0; nt < 3; ++nt) {
      int n = wn * 48 + nt * 16 + col;
      #pragma unroll
      for (int r = 0; r < 4; ++r) {
        int m = wm * 96 + mt * 16 + q4 + r;      // window row
        unsigned short h = f2bf(acc[mt][nt][r] + bov[nt]);
        if (n < 64) {
          bool isq = (wm == 0) ? (mt >= 4) : (mt < 2);
          if (isq) PsU[(m - 64) * 72 + n] = h;
        } else if (n < 128) {
          Kl[m * 72 + (n - 64)] = h;
        } else {
          Vt[(n - 128) * 216 + m] = h;
        }
      }
    }
  }
  if (t < 256) { // zero-fill Vt j-cols 192..207 (PV k-chunk overhang)
    int pz = t >> 2, c0 = 192 + (t & 3) * 4;
    *(uint2*)(Vt + pz * 216 + c0) = make_uint2(0u, 0u);
  }
  BAR_LGKM();

  // ---- phase 2: banded attention ----
  int p = w >> 1, s = w & 1;
  int iq = i0 + p * 16;
  bf16x8 aq0 = *(const bf16x8*)(PsU + (p * 16 + col) * 72 + quad * 8);
  bf16x8 aq1 = *(const bf16x8*)(PsU + (p * 16 + col) * 72 + 32 + quad * 8);

  // QK^T: wave's j-tile subset (s=0: t9 0..4, s=1: t9 5..8)
  int nt9 = 5 - s, t9b = 5 * s;
  f32x4 sv[5];
  for (int i = 0; i < nt9; ++i) {
    int t9 = t9b + i;
    int krow = ((p + t9) * 16 + col) * 72;
    bf16x8 kb0 = *(const bf16x8*)(Kl + krow + quad * 8);
    bf16x8 kb1 = *(const bf16x8*)(Kl + krow + 32 + quad * 8);
    f32x4 z = {};
    z = __builtin_amdgcn_mfma_f32_16x16x32_bf16(aq0, kb0, z, 0, 0, 0);
    sv[i] = __builtin_amdgcn_mfma_f32_16x16x32_bf16(aq1, kb1, z, 0, 0, 0);
  }
  float mrow[4] = {-3e38f, -3e38f, -3e38f, -3e38f};
  for (int i = 0; i < nt9; ++i) {
    int t9 = t9b + i;
    int j = iq - 64 + t9 * 16 + col;
    #pragma unroll
    for (int r = 0; r < 4; ++r) {
      int diff = q4 + r + 64 - t9 * 16 - col;   // i - j
      bool valid = (j >= 0) & (j < 2048) & (diff >= -64) & (diff <= 64);
      int bi = 64 - diff; bi = bi < 0 ? 0 : (bi > 128 ? 128 : bi);
      float x = valid ? (sv[i][r] * 0.125f + biasL[bi]) : -3e38f;
      sv[i][r] = x;
      mrow[r] = fmaxf(mrow[r], x);
    }
  }
  #pragma unroll
  for (int r = 0; r < 4; ++r) ROW16_MAX(mrow[r]);
  if (col == 0) {
    #pragma unroll
    for (int r = 0; r < 4; ++r) Mx[w * 16 + q4 + r] = mrow[r];
  }
  BAR_LGKM();
  #pragma unroll
  for (int r = 0; r < 4; ++r) mrow[r] = fmaxf(mrow[r], Mx[(w ^ 1) * 16 + q4 + r]);

  unsigned short* Pw = PsU + p * 2688;       // 16 rows x 168 per pair
  float lsum[4] = {0.f, 0.f, 0.f, 0.f};
  for (int i = 0; i < nt9; ++i) {
    int t9 = t9b + i;
    #pragma unroll
    for (int r = 0; r < 4; ++r) {
      float pe = __expf(sv[i][r] - mrow[r]);
      lsum[r] += pe;
      Pw[(q4 + r) * 168 + t9 * 16 + col] = f2bf(pe);
    }
  }
  #pragma unroll
  for (int r = 0; r < 4; ++r) ROW16_SUM(lsum[r]);
  if (col == 0) {
    #pragma unroll
    for (int r = 0; r < 4; ++r) Lx[w * 16 + q4 + r] = lsum[r];
  }
  if (s == 0) {
    #pragma unroll
    for (int r = 0; r < 4; ++r) Pw[(q4 + r) * 168 + 144 + col] = 0;
  }
  BAR_LGKM();
  #pragma unroll
  for (int r = 0; r < 4; ++r) lsum[r] += Lx[(w ^ 1) * 16 + q4 + r];

  // PV split by OUTPUT p-tiles (no cross-wave O reduction needed):
  // wave handles nt = s*2 + {0,1} over ALL 5 k-chunks.
  f32x4 o[2] = {};
  #pragma unroll
  for (int kc = 0; kc < 5; ++kc) {
    bf16x8 pa = *(const bf16x8*)(Pw + col * 168 + kc * 32 + quad * 8);
    #pragma unroll
    for (int n2 = 0; n2 < 2; ++n2) {
      bf16x8 vb = *(const bf16x8*)(Vt + ((s * 2 + n2) * 16 + col) * 216 + 16 * p + kc * 32 + quad * 8);
      o[n2] = __builtin_amdgcn_mfma_f32_16x16x32_bf16(pa, vb, o[n2], 0, 0, 0);
    }
  }
  BAR_LGKM();   // all P reads drained before Obf overwrites PsU
  {
    float rl[4];
    #pragma unroll
    for (int r = 0; r < 4; ++r) rl[r] = 1.0f / lsum[r];
    #pragma unroll
    for (int n2 = 0; n2 < 2; ++n2)
      #pragma unroll
      for (int r = 0; r < 4; ++r)
        PsU[(p * 16 + q4 + r) * 72 + s * 32 + n2 * 16 + col] = f2bf(o[n2][r] * rl[r]);
  }
  BAR_LGKM();

  // ---- phase 3: out[64 q][1024 n] = Obf @ Wot + bo ----
  // wave w owns n-cols [w*128, w*128+128); Wot slice loaded here (L2/L3-hot,
  // 2nd block on CU covers the latency).
  const unsigned short* wb_base = Wot + (size_t)(w * 128 + col) * 64 + quad * 8;
  bf16x8 wb[8][2];
  #pragma unroll
  for (int ns = 0; ns < 8; ++ns) {
    wb[ns][0] = *(const bf16x8*)(wb_base + ns * 16 * 64);
    wb[ns][1] = *(const bf16x8*)(wb_base + ns * 16 * 64 + 32);
  }
  float bov8[8];
  #pragma unroll
  for (int ns = 0; ns < 8; ++ns) bov8[ns] = bo[w * 128 + ns * 16 + col];
  float* outbase = out + ((size_t)(b << 11) + i0) * 1024 + w * 128;
  #pragma unroll
  for (int mt = 0; mt < 4; ++mt) {
    bf16x8 a0 = *(const bf16x8*)(PsU + (mt * 16 + col) * 72 + quad * 8);
    bf16x8 a1 = *(const bf16x8*)(PsU + (mt * 16 + col) * 72 + 32 + quad * 8);
    f32x4 acc8[8] = {};
    #pragma unroll
    for (int ns = 0; ns < 8; ++ns) {
      acc8[ns] = __builtin_amdgcn_mfma_f32_16x16x32_bf16(a0, wb[ns][0], acc8[ns], 0, 0, 0);
      acc8[ns] = __builtin_amdgcn_mfma_f32_16x16x32_bf16(a1, wb[ns][1], acc8[ns], 0, 0, 0);
    }
    #pragma unroll
    for (int ns = 0; ns < 8; ++ns)
      #pragma unroll
      for (int r = 0; r < 4; ++r)
        outbase[(size_t)(mt * 16 + q4 + r) * 1024 + ns * 16 + col] = acc8[ns][r] + bov8[ns];
  }
}

// ---------------- launch ----------------
extern "C" void kernel_launch(void* const* d_in, const int* in_sizes, int n_in,
                              void* d_out, int out_size, void* d_ws, size_t ws_size,
                              hipStream_t stream) {
  const float* X    = (const float*)d_in[0];
  // d_in[1] = attention_mask: per-row constant shift -> softmax-invariant, unused
  const float* Wq   = (const float*)d_in[2];
  const float* bq   = (const float*)d_in[3];
  const float* Wk   = (const float*)d_in[4];
  const float* bk   = (const float*)d_in[5];
  const float* Wv   = (const float*)d_in[6];
  const float* bv   = (const float*)d_in[7];
  const float* Wo   = (const float*)d_in[8];
  const float* bo   = (const float*)d_in[9];
  const float* bias = (const float*)d_in[10];
  float* out = (float*)d_out;
  char* ws = (char*)d_ws;
  unsigned short* Wt   = (unsigned short*)(ws);              //   393,216 B
  unsigned short* Wot  = (unsigned short*)(ws + 393216);     //   131,072 B
  float*          bqkv = (float*)(ws + 524288);              //       768 B

  prep_kernel<<<1025, 256, 0, stream>>>(Wq, Wk, Wv, Wo, bq, bk, bv, Wt, Wot, bqkv);
  fused_attn<<<256, 512, 0, stream>>>(X, Wt, bqkv, bias, Wot, bo, out);
}

// Round 8
// 159.518 us; speedup vs baseline: 1.2054x; 1.2054x over previous
//
#include <hip/hip_runtime.h>

// ---------------- types / helpers ----------------
using bf16x8 = __attribute__((ext_vector_type(8))) short;
using f32x4  = __attribute__((ext_vector_type(4))) float;

static __device__ inline unsigned short f2bf(float f) {
  unsigned int u = __float_as_uint(f);
  u += 0x7fffu + ((u >> 16) & 1u);          // round-to-nearest-even
  return (unsigned short)(u >> 16);
}
static __device__ inline unsigned int pk2(float a, float b) {
  return (unsigned int)f2bf(a) | ((unsigned int)f2bf(b) << 16);
}

// Barrier draining LDS ops only; global loads (vmcnt) stay in flight.
#define BAR_LGKM() { asm volatile("s_waitcnt lgkmcnt(0)" ::: "memory"); \
                     __builtin_amdgcn_sched_barrier(0); \
                     __builtin_amdgcn_s_barrier(); }

// butterfly reductions across the 16-lane DPP row (row_ror 1,2,4,8)
#define ROW16_MAX(x) { \
  { int _t = __builtin_amdgcn_update_dpp(0, __float_as_int(x), 0x121, 0xf, 0xf, true); x = fmaxf(x, __int_as_float(_t)); } \
  { int _t = __builtin_amdgcn_update_dpp(0, __float_as_int(x), 0x122, 0xf, 0xf, true); x = fmaxf(x, __int_as_float(_t)); } \
  { int _t = __builtin_amdgcn_update_dpp(0, __float_as_int(x), 0x124, 0xf, 0xf, true); x = fmaxf(x, __int_as_float(_t)); } \
  { int _t = __builtin_amdgcn_update_dpp(0, __float_as_int(x), 0x128, 0xf, 0xf, true); x = fmaxf(x, __int_as_float(_t)); } }
#define ROW16_SUM(x) { \
  { int _t = __builtin_amdgcn_update_dpp(0, __float_as_int(x), 0x121, 0xf, 0xf, true); x += __int_as_float(_t); } \
  { int _t = __builtin_amdgcn_update_dpp(0, __float_as_int(x), 0x122, 0xf, 0xf, true); x += __int_as_float(_t); } \
  { int _t = __builtin_amdgcn_update_dpp(0, __float_as_int(x), 0x124, 0xf, 0xf, true); x += __int_as_float(_t); } \
  { int _t = __builtin_amdgcn_update_dpp(0, __float_as_int(x), 0x128, 0xf, 0xf, true); x += __int_as_float(_t); } }

// ---------------- kernel 0: weight prep (transpose -> bf16) ----------------
__global__ __launch_bounds__(256) void prep_kernel(
    const float* __restrict__ Wq, const float* __restrict__ Wk, const float* __restrict__ Wv,
    const float* __restrict__ Wo, const float* __restrict__ bq, const float* __restrict__ bk,
    const float* __restrict__ bv,
    unsigned short* __restrict__ Wt, unsigned short* __restrict__ Wot, float* __restrict__ bqkv)
{
  int idx = blockIdx.x * 256 + threadIdx.x;
  if (idx < 192 * 1024) {
    int n = idx >> 10, k = idx & 1023;
    const float* W = (n < 64) ? Wq : (n < 128) ? Wk : Wv;
    Wt[idx] = f2bf(W[k * 64 + (n & 63)]);
  } else if (idx < 192 * 1024 + 1024 * 64) {
    int j = idx - 192 * 1024;
    int n = j >> 6, k = j & 63;
    Wot[j] = f2bf(Wo[k * 1024 + n]);
  } else if (idx < 192 * 1024 + 1024 * 64 + 192) {
    int n = idx - (192 * 1024 + 1024 * 64);
    bqkv[n] = (n < 64) ? bq[n] : (n < 128) ? bk[n - 64] : bv[n - 128];
  }
}

// ---------------- fused kernel: QKV proj + banded attention + out proj ----------------
// Block = 64 q-rows, grid 256 (1 block/CU), 1024 threads = 16 waves (4/SIMD).
// Phase 1: window GEMM [192 rows] x [192 qkv] x K=1024, BK=64 dbuf, reg prefetch.
// Phase 2: banded attention; 4 q-subtiles (g) x 4 worker waves (u) each.
// Phase 3: output projection; wave w owns 64 n-cols.
// LDS map (bytes):
//   phase 1: A dbuf [0, 55296), B dbuf [55296, 110592)   (192 x 72 shorts each)
//   phase 2: Kl [0, 27648), Vt [27648, 55296),
//            PsU [55296, 76800)  time-muxed: Q(64x72) -> P(4x16x168) -> Obf(64x72)
//   always : Mx [110592), Lx [111616), biasL [112640)   (outside phase-1 region)
__global__ __launch_bounds__(1024, 4) void fused_attn(
    const float* __restrict__ X, const unsigned short* __restrict__ Wt,
    const float* __restrict__ bqkv, const float* __restrict__ bias,
    const unsigned short* __restrict__ Wot, const float* __restrict__ bo,
    float* __restrict__ out)
{
  __shared__ __align__(16) char smem[113664];
  unsigned short* const Kl  = (unsigned short*)(smem);            // [192][72]
  unsigned short* const Vt  = (unsigned short*)(smem + 27648);    // [64][216]
  unsigned short* const PsU = (unsigned short*)(smem + 55296);    // Q / P / Obf
  float* const Mx    = (float*)(smem + 110592);                   // [16][16]
  float* const Lx    = (float*)(smem + 111616);                   // [16][16]
  float* const biasL = (float*)(smem + 112640);                   // [129]
  unsigned short* const As_ = (unsigned short*)(smem);            // [2][192*72]
  unsigned short* const Bs_ = (unsigned short*)(smem + 55296);    // [2][192*72]

  int t = threadIdx.x;
  int lane = t & 63, w = t >> 6;
  int col = lane & 15, quad = lane >> 4, q4 = quad * 4;
  // XCD swizzle: each XCD gets one batch's 32 contiguous q-tiles (halo L2 reuse).
  int L = ((blockIdx.x & 7) << 5) | (blockIdx.x >> 3);
  int b = L >> 5;                    // batch
  int i0 = (L & 31) * 64;            // first q row (batch coords)
  const float* xbase = X + (size_t)(b << 11) * 1024;

  if (t < 129) biasL[t] = bias[1984 + t];   // region untouched by phase 1

  // ---- phase 1: window GEMM, BK=64, double-buffered, reg prefetch ----
  int wm = w >> 2, wn = w & 3;       // wave tile: 48 rows x 48 cols
  f32x4 acc[3][3] = {};
  int tr = t >> 4, c4 = t & 15;      // staging: 64 rows/slab, 16 chunks of 4
  int offA[3], offB[3];
  #pragma unroll
  for (int i = 0; i < 3; ++i) {
    int row = i * 64 + tr;           // window row 0..191
    int jb = i0 - 64 + row;
    int jc = jb < 0 ? 0 : (jb > 2047 ? 2047 : jb);
    offA[i] = jc * 1024 + c4 * 4;
    offB[i] = row * 1024 + c4 * 4;
  }
  float bov[3];
  #pragma unroll
  for (int nt = 0; nt < 3; ++nt) bov[nt] = bqkv[wn * 48 + nt * 16 + col];

  float4 pA[3]; uint2 pB[3];
  #pragma unroll
  for (int i = 0; i < 3; ++i) {
    pA[i] = *(const float4*)(xbase + offA[i]);
    pB[i] = *(const uint2*)(Wt + offB[i]);
  }
  for (int ks = 0; ks < 16; ++ks) {
    unsigned short* A  = As_ + (ks & 1) * 13824;
    unsigned short* Bb = Bs_ + (ks & 1) * 13824;
    #pragma unroll
    for (int i = 0; i < 3; ++i) {    // staged regs -> LDS[cur]
      *(uint2*)(A  + (i * 64 + tr) * 72 + c4 * 4) =
          make_uint2(pk2(pA[i].x, pA[i].y), pk2(pA[i].z, pA[i].w));
      *(uint2*)(Bb + (i * 64 + tr) * 72 + c4 * 4) = pB[i];
    }
    if (ks + 1 < 16) {               // next tile's loads issued before barrier
      #pragma unroll
      for (int i = 0; i < 3; ++i) {
        pA[i] = *(const float4*)(xbase + offA[i] + (ks + 1) * 64);
        pB[i] = *(const uint2*)(Wt + offB[i] + (ks + 1) * 64);
      }
    }
    BAR_LGKM();
    // race-free: a wave's buf-X ds_reads drain (own lgkmcnt 0) before it
    // signals the next barrier; buf-X is rewritten 2 iters later, after it.
    #pragma unroll
    for (int kk = 0; kk < 64; kk += 32) {
      int ko = kk + quad * 8;
      bf16x8 bfr[3];
      #pragma unroll
      for (int nt = 0; nt < 3; ++nt)
        bfr[nt] = *(const bf16x8*)(Bb + ((wn * 3 + nt) * 16 + col) * 72 + ko);
      #pragma unroll
      for (int mt = 0; mt < 3; ++mt) {
        bf16x8 afr = *(const bf16x8*)(A + ((wm * 3 + mt) * 16 + col) * 72 + ko);
        #pragma unroll
        for (int nt = 0; nt < 3; ++nt)
          acc[mt][nt] = __builtin_amdgcn_mfma_f32_16x16x32_bf16(afr, bfr[nt], acc[mt][nt], 0, 0, 0);
      }
    }
  }
  BAR_LGKM();        // last-buf ds_reads done before LDS repurpose

  // ---- phase 1b: accumulators (+bias, ->bf16) into phase-2 layouts ----
  #pragma unroll
  for (int mt = 0; mt < 3; ++mt) {
    #pragma unroll
    for (int nt = 0; nt < 3; ++nt) {
      int n = wn * 48 + nt * 16 + col;
      #pragma unroll
      for (int r = 0; r < 4; ++r) {
        int m = wm * 48 + mt * 16 + q4 + r;      // window row
        unsigned short h = f2bf(acc[mt][nt][r] + bov[nt]);
        if (n < 64) {
          if (m >= 64 && m < 128) PsU[(m - 64) * 72 + n] = h;   // Q
        } else if (n < 128) {
          Kl[m * 72 + (n - 64)] = h;                            // K
        } else {
          Vt[(n - 128) * 216 + m] = h;                          // V^T
        }
      }
    }
  }
  if (t < 256) { // zero-fill Vt j-cols 192..207 (PV k-chunk overhang)
    int pz = t >> 2, c0 = 192 + (t & 3) * 4;
    *(uint2*)(Vt + pz * 216 + c0) = make_uint2(0u, 0u);
  }
  BAR_LGKM();

  // ---- phase 2: banded attention; g = q-subtile (16 rows), u = worker ----
  int g = w >> 2, u = w & 3;
  int iq = i0 + g * 16;
  bf16x8 aq0 = *(const bf16x8*)(PsU + (g * 16 + col) * 72 + quad * 8);
  bf16x8 aq1 = *(const bf16x8*)(PsU + (g * 16 + col) * 72 + 32 + quad * 8);

  // QK^T: j-tiles split u=0:{0,1,2} u=1:{3,4} u=2:{5,6} u=3:{7,8}
  int nt9 = (u == 0) ? 3 : 2;
  int t9b = (u == 0) ? 0 : (2 * u + 1);
  f32x4 sv[3];
  for (int i = 0; i < nt9; ++i) {
    int t9 = t9b + i;
    int krow = ((g + t9) * 16 + col) * 72;
    bf16x8 kb0 = *(const bf16x8*)(Kl + krow + quad * 8);
    bf16x8 kb1 = *(const bf16x8*)(Kl + krow + 32 + quad * 8);
    f32x4 z = {};
    z = __builtin_amdgcn_mfma_f32_16x16x32_bf16(aq0, kb0, z, 0, 0, 0);
    sv[i] = __builtin_amdgcn_mfma_f32_16x16x32_bf16(aq1, kb1, z, 0, 0, 0);
  }
  float mrow[4] = {-3e38f, -3e38f, -3e38f, -3e38f};
  for (int i = 0; i < nt9; ++i) {
    int t9 = t9b + i;
    int j = iq - 64 + t9 * 16 + col;
    #pragma unroll
    for (int r = 0; r < 4; ++r) {
      int diff = q4 + r + 64 - t9 * 16 - col;   // i - j
      bool valid = (j >= 0) & (j < 2048) & (diff >= -64) & (diff <= 64);
      int bi = 64 - diff; bi = bi < 0 ? 0 : (bi > 128 ? 128 : bi);
      float x = valid ? (sv[i][r] * 0.125f + biasL[bi]) : -3e38f;
      sv[i][r] = x;
      mrow[r] = fmaxf(mrow[r], x);
    }
  }
  #pragma unroll
  for (int r = 0; r < 4; ++r) ROW16_MAX(mrow[r]);
  if (col == 0) {
    #pragma unroll
    for (int r = 0; r < 4; ++r) Mx[w * 16 + q4 + r] = mrow[r];
  }
  BAR_LGKM();
  #pragma unroll
  for (int r = 0; r < 4; ++r) {
    float m0_ = Mx[(g * 4 + 0) * 16 + q4 + r];
    float m1_ = Mx[(g * 4 + 1) * 16 + q4 + r];
    float m2_ = Mx[(g * 4 + 2) * 16 + q4 + r];
    float m3_ = Mx[(g * 4 + 3) * 16 + q4 + r];
    mrow[r] = fmaxf(fmaxf(m0_, m1_), fmaxf(m2_, m3_));
  }

  unsigned short* Pw = PsU + g * 2688;       // 16 rows x 168
  float lsum[4] = {0.f, 0.f, 0.f, 0.f};
  for (int i = 0; i < nt9; ++i) {
    int t9 = t9b + i;
    #pragma unroll
    for (int r = 0; r < 4; ++r) {
      float pe = __expf(sv[i][r] - mrow[r]);
      lsum[r] += pe;
      Pw[(q4 + r) * 168 + t9 * 16 + col] = f2bf(pe);
    }
  }
  #pragma unroll
  for (int r = 0; r < 4; ++r) ROW16_SUM(lsum[r]);
  if (col == 0) {
    #pragma unroll
    for (int r = 0; r < 4; ++r) Lx[w * 16 + q4 + r] = lsum[r];
  }
  if (u == 0) {
    #pragma unroll
    for (int r = 0; r < 4; ++r) Pw[(q4 + r) * 168 + 144 + col] = 0;
  }
  BAR_LGKM();
  #pragma unroll
  for (int r = 0; r < 4; ++r)
    lsum[r] = Lx[(g * 4 + 0) * 16 + q4 + r] + Lx[(g * 4 + 1) * 16 + q4 + r]
            + Lx[(g * 4 + 2) * 16 + q4 + r] + Lx[(g * 4 + 3) * 16 + q4 + r];

  // PV: wave u owns p-block u (16 cols) over all 5 k-chunks
  f32x4 o = {};
  #pragma unroll
  for (int kc = 0; kc < 5; ++kc) {
    bf16x8 pa = *(const bf16x8*)(Pw + col * 168 + kc * 32 + quad * 8);
    bf16x8 vb = *(const bf16x8*)(Vt + (u * 16 + col) * 216 + g * 16 + kc * 32 + quad * 8);
    o = __builtin_amdgcn_mfma_f32_16x16x32_bf16(pa, vb, o, 0, 0, 0);
  }
  BAR_LGKM();   // all P reads drained before Obf overwrites PsU
  {
    float rl[4];
    #pragma unroll
    for (int r = 0; r < 4; ++r) rl[r] = 1.0f / lsum[r];
    #pragma unroll
    for (int r = 0; r < 4; ++r)
      PsU[(g * 16 + q4 + r) * 72 + u * 16 + col] = f2bf(o[r] * rl[r]);
  }
  BAR_LGKM();

  // ---- phase 3: out[64 q][1024 n] = Obf @ Wot + bo; wave owns 64 n-cols ----
  int n0 = w * 64;
  const unsigned short* wb_base = Wot + (size_t)(n0 + col) * 64 + quad * 8;
  bf16x8 wb[4][2];
  #pragma unroll
  for (int ns = 0; ns < 4; ++ns) {
    wb[ns][0] = *(const bf16x8*)(wb_base + ns * 16 * 64);
    wb[ns][1] = *(const bf16x8*)(wb_base + ns * 16 * 64 + 32);
  }
  float bov4[4];
  #pragma unroll
  for (int ns = 0; ns < 4; ++ns) bov4[ns] = bo[n0 + ns * 16 + col];
  float* outbase = out + ((size_t)(b << 11) + i0) * 1024 + n0;
  #pragma unroll
  for (int mt = 0; mt < 4; ++mt) {
    bf16x8 a0 = *(const bf16x8*)(PsU + (mt * 16 + col) * 72 + quad * 8);
    bf16x8 a1 = *(const bf16x8*)(PsU + (mt * 16 + col) * 72 + 32 + quad * 8);
    f32x4 a4[4] = {};
    #pragma unroll
    for (int ns = 0; ns < 4; ++ns) {
      a4[ns] = __builtin_amdgcn_mfma_f32_16x16x32_bf16(a0, wb[ns][0], a4[ns], 0, 0, 0);
      a4[ns] = __builtin_amdgcn_mfma_f32_16x16x32_bf16(a1, wb[ns][1], a4[ns], 0, 0, 0);
    }
    #pragma unroll
    for (int ns = 0; ns < 4; ++ns)
      #pragma unroll
      for (int r = 0; r < 4; ++r)
        outbase[(size_t)(mt * 16 + q4 + r) * 1024 + ns * 16 + col] = a4[ns][r] + bov4[ns];
  }
}

// ---------------- launch ----------------
extern "C" void kernel_launch(void* const* d_in, const int* in_sizes, int n_in,
                              void* d_out, int out_size, void* d_ws, size_t ws_size,
                              hipStream_t stream) {
  const float* X    = (const float*)d_in[0];
  // d_in[1] = attention_mask: per-row constant shift -> softmax-invariant, unused
  const float* Wq   = (const float*)d_in[2];
  const float* bq   = (const float*)d_in[3];
  const float* Wk   = (const float*)d_in[4];
  const float* bk   = (const float*)d_in[5];
  const float* Wv   = (const float*)d_in[6];
  const float* bv   = (const float*)d_in[7];
  const float* Wo   = (const float*)d_in[8];
  const float* bo   = (const float*)d_in[9];
  const float* bias = (const float*)d_in[10];
  float* out = (float*)d_out;
  char* ws = (char*)d_ws;
  unsigned short* Wt   = (unsigned short*)(ws);              //   393,216 B
  unsigned short* Wot  = (unsigned short*)(ws + 393216);     //   131,072 B
  float*          bqkv = (float*)(ws + 524288);              //       768 B

  prep_kernel<<<1025, 256, 0, stream>>>(Wq, Wk, Wv, Wo, bq, bk, bv, Wt, Wot, bqkv);
  fused_attn<<<256, 1024, 0, stream>>>(X, Wt, bqkv, bias, Wot, bo, out);
}